// Round 13
// baseline (70.250 us; speedup 1.0000x reference)
//
#include <hip/hip_runtime.h>

#define BB 64
#define TT 2048
#define HH 512
#define NROWS (BB * TT)
#define CS 16     // lstm: output steps per chunk
#define WU 32     // lstm: zero-state warmup steps
#define NST (CS + WU)        // staged steps per block (48)
#define NCHUNK (TT / CS)     // 128 blocks over time

#define NLOG2E  (-1.4426950408889634f)
#define N2LOG2E (-2.8853900817779268f)

typedef float f32x4 __attribute__((ext_vector_type(4)));

// sigmoid(x) where zs = -x*log2(e):   1/(1+2^zs)
static __device__ __forceinline__ float sigm2(float zs) {
  return __builtin_amdgcn_rcpf(1.0f + __builtin_amdgcn_exp2f(zs));
}
// tanh(x) where zs = -2x*log2(e):     2/(1+2^zs) - 1
static __device__ __forceinline__ float tanh2(float zs) {
  return fmaf(2.0f, __builtin_amdgcn_rcpf(1.0f + __builtin_amdgcn_exp2f(zs)), -1.0f);
}
static __device__ __forceinline__ float dot4(f32x4 a, f32x4 b) {
  return fmaf(a.x, b.x, fmaf(a.y, b.y, fmaf(a.z, b.z, a.w * b.w)));
}
// merge-tree reduce: lane%4==c ends up holding sum of a_c over all 64 lanes
static __device__ __forceinline__ float merge_reduce(float a0, float a1, float a2,
                                                     float a3, int lane) {
  float x01 = (lane & 1) ? a1 : a0;
  float y01 = (lane & 1) ? a0 : a1;
  x01 += __shfl_xor(y01, 1, 64);
  float x23 = (lane & 1) ? a3 : a2;
  float y23 = (lane & 1) ? a2 : a3;
  x23 += __shfl_xor(y23, 1, 64);
  float xm = (lane & 2) ? x23 : x01;
  float ym = (lane & 2) ? x01 : x23;
  xm += __shfl_xor(ym, 2, 64);
#pragma unroll
  for (int off = 4; off < 64; off <<= 1) xm += __shfl_xor(xm, off, 64);
  return xm;
}
// async global->LDS: LDS dest is wave-uniform base, HW adds lane*size
static __device__ __forceinline__ void gl16(const float* g, float* l) {
  __builtin_amdgcn_global_load_lds((__attribute__((address_space(1))) const void*)(g),
                                   (__attribute__((address_space(3))) void*)(l), 16, 0, 0);
}
static __device__ __forceinline__ void gl4(const float* g, float* l) {
  __builtin_amdgcn_global_load_lds((__attribute__((address_space(1))) const void*)(g),
                                   (__attribute__((address_space(3))) void*)(l), 4, 0, 0);
}
static __device__ __forceinline__ f32x4 ntload4(const float* p) {
  return __builtin_nontemporal_load((const f32x4*)p);
}

// Kernel A: projections + where(worry) + LSTM input pre-activations.
// One wave per QUAD of (b,t) rows: 8 nontemporal loads preissued (8KB in
// flight/wave), 4 independent merge-trees (ILP=4 on the DS chain), then a
// PARALLEL tail: lane = 16g+k computes row r0+g's ws element k (full-lane
// occupancy, one scatter store for 4x64B).
// ws layout [T][B][16]: u1[0..7] (p1 gates pre-scaled), u2[0..3] (p2), d0, d1, 0, 0.
__global__ __launch_bounds__(256) void proj_kernel(
    const float* __restrict__ x, const int* __restrict__ worry,
    const float* __restrict__ Wnw, const float* __restrict__ bnw,
    const float* __restrict__ Ww,  const float* __restrict__ bw,
    const float* __restrict__ Wih1, const float* __restrict__ bih1, const float* __restrict__ bhh1,
    const float* __restrict__ Wih2, const float* __restrict__ bih2, const float* __restrict__ bhh2,
    float* __restrict__ out_nw, float* __restrict__ ws)
{
  const int lane = threadIdx.x & 63;
  const int wid  = blockIdx.x * (blockDim.x >> 6) + (threadIdx.x >> 6);
  const int nwv  = gridDim.x * (blockDim.x >> 6);
  const int cb   = lane * 4;
  const int g    = lane >> 4;      // tail: row group 0..3
  const int k    = lane & 15;      // tail: ws element 0..15

  const f32x4 wa0 = *(const f32x4*)(Wnw + cb);
  const f32x4 wb0 = *(const f32x4*)(Wnw + 256 + cb);
  const f32x4 wa1 = *(const f32x4*)(Wnw + 512 + cb);
  const f32x4 wb1 = *(const f32x4*)(Wnw + 768 + cb);
  const f32x4 va0 = *(const f32x4*)(Ww  + cb);
  const f32x4 vb0 = *(const f32x4*)(Ww  + 256 + cb);
  const f32x4 va1 = *(const f32x4*)(Ww  + 512 + cb);
  const f32x4 vb1 = *(const f32x4*)(Ww  + 768 + cb);

  // per-lane tail constants: element k of a ws row
  float V0 = 0.f, V1 = 0.f, Bk = 0.f;
  bool selW = false;   // true: input is (w0,w1); false: (d0,d1)
  if (k < 8) {
    const float s = (k == 4 || k == 5) ? N2LOG2E : NLOG2E;
    V0 = s * Wih1[2 * k];
    V1 = s * Wih1[2 * k + 1];
    Bk = s * (bih1[k] + bhh1[k]);
  } else if (k < 12) {
    const int kk = k - 8;
    const float s = (kk == 2) ? N2LOG2E : NLOG2E;
    V0 = s * Wih2[2 * kk];
    V1 = s * Wih2[2 * kk + 1];
    Bk = s * (bih2[kk] + bhh2[kk]);
    selW = true;
  } else if (k == 12) { V0 = 1.f; }
  else if (k == 13) { V1 = 1.f; }
  const float bn0 = bnw[0], bn1 = bnw[1], bw0 = bw[0], bw1 = bw[1];

  for (int r0 = 4 * wid; r0 < NROWS; r0 += 4 * nwv) {
    const float* xr0 = x + (size_t)r0 * HH;
    // 8 loads preissued: 8KB in flight per wave
    const f32x4 xa0 = ntload4(xr0 + cb);
    const f32x4 xb0 = ntload4(xr0 + 256 + cb);
    const f32x4 xa1 = ntload4(xr0 + HH + cb);
    const f32x4 xb1 = ntload4(xr0 + HH + 256 + cb);
    const f32x4 xa2 = ntload4(xr0 + 2 * HH + cb);
    const f32x4 xb2 = ntload4(xr0 + 2 * HH + 256 + cb);
    const f32x4 xa3 = ntload4(xr0 + 3 * HH + cb);
    const f32x4 xb3 = ntload4(xr0 + 3 * HH + 256 + cb);

    const float xmP = merge_reduce(dot4(xa0, wa0) + dot4(xb0, wb0),
                                   dot4(xa0, wa1) + dot4(xb0, wb1),
                                   dot4(xa0, va0) + dot4(xb0, vb0),
                                   dot4(xa0, va1) + dot4(xb0, vb1), lane);
    const float xmQ = merge_reduce(dot4(xa1, wa0) + dot4(xb1, wb0),
                                   dot4(xa1, wa1) + dot4(xb1, wb1),
                                   dot4(xa1, va0) + dot4(xb1, vb0),
                                   dot4(xa1, va1) + dot4(xb1, vb1), lane);
    const float xmR = merge_reduce(dot4(xa2, wa0) + dot4(xb2, wb0),
                                   dot4(xa2, wa1) + dot4(xb2, wb1),
                                   dot4(xa2, va0) + dot4(xb2, vb0),
                                   dot4(xa2, va1) + dot4(xb2, vb1), lane);
    const float xmS = merge_reduce(dot4(xa3, wa0) + dot4(xb3, wb0),
                                   dot4(xa3, wa1) + dot4(xb3, wb1),
                                   dot4(xa3, va0) + dot4(xb3, vb0),
                                   dot4(xa3, va1) + dot4(xb3, vb1), lane);

    const float P0 = __shfl(xmP, 0, 64), P1 = __shfl(xmP, 1, 64);
    const float P2 = __shfl(xmP, 2, 64), P3 = __shfl(xmP, 3, 64);
    const float Q0 = __shfl(xmQ, 0, 64), Q1 = __shfl(xmQ, 1, 64);
    const float Q2 = __shfl(xmQ, 2, 64), Q3 = __shfl(xmQ, 3, 64);
    const float R0 = __shfl(xmR, 0, 64), R1 = __shfl(xmR, 1, 64);
    const float R2 = __shfl(xmR, 2, 64), R3 = __shfl(xmR, 3, 64);
    const float S0 = __shfl(xmS, 0, 64), S1 = __shfl(xmS, 1, 64);
    const float S2 = __shfl(xmS, 2, 64), S3 = __shfl(xmS, 3, 64);

    // per-lane A-select for this lane's row group g
    const float A0 = (g == 0) ? P0 : (g == 1) ? Q0 : (g == 2) ? R0 : S0;
    const float A1 = (g == 0) ? P1 : (g == 1) ? Q1 : (g == 2) ? R1 : S1;
    const float A2 = (g == 0) ? P2 : (g == 1) ? Q2 : (g == 2) ? R2 : S2;
    const float A3 = (g == 0) ? P3 : (g == 1) ? Q3 : (g == 2) ? R3 : S3;

    const int r = r0 + g;
    const bool useW = selW || (worry[r] != 0);   // worry is int32 (bool->int)
    const float in0 = useW ? (A2 + bw0) : (A0 + bn0);
    const float in1 = useW ? (A3 + bw1) : (A1 + bn1);
    const float u = fmaf(V0, in0, fmaf(V1, in1, Bk));

    // scatter store: 4 rows x 64B (one instr, 4 transactions)
    ws[(((size_t)(r & (TT - 1)) * BB) + (r >> 11)) * 16 + k] = u;
    if (k == 12 || k == 13) out_nw[(size_t)r * 2 + (k - 12)] = u;
  }
}

// Kernel B: time-parallel speculative chunks with LDS-staged inputs (r10).
__global__ __launch_bounds__(64) void lstm_kernel(
    const float* __restrict__ ws, const int* __restrict__ lengths,
    const float* __restrict__ Whh1, const float* __restrict__ Whh2,
    float* __restrict__ out_adj)
{
  __shared__ f32x4 SU[NST][3][64];       // 48*3*64*16 = 147456 B
  __shared__ float SNW0[CS][64];         // 4096 B
  __shared__ float SNW1[CS][64];         // 4096 B   (total 155648 <= 160 KiB)

  const int b = threadIdx.x;             // 0..63 (lane == batch)
  const int chunk = blockIdx.x;
  const int tbeg = chunk * CS;
  const int tw   = (tbeg >= WU) ? (tbeg - WU) : 0;
  const int sbeg = tbeg - tw;            // first stored s (0 for chunk 0)
  const int nst  = sbeg + CS;            // staged steps this block

  // phase 0: async-stage the whole window (no VGPR dests -> cannot be sunk)
  for (int s = 0; s < nst; ++s) {
    const float* row = ws + ((size_t)(tw + s) * BB + b) * 16;  // per-lane src
    gl16(row,     (float*)&SU[s][0][0]);
    gl16(row + 4, (float*)&SU[s][1][0]);
    gl16(row + 8, (float*)&SU[s][2][0]);
    if (s >= sbeg) {
      gl4(row + 12, &SNW0[s - sbeg][0]);
      gl4(row + 13, &SNW1[s - sbeg][0]);
    }
  }

  float A[8][2];
#pragma unroll
  for (int k = 0; k < 8; ++k) {
    const float s = (k == 4 || k == 5) ? N2LOG2E : NLOG2E;
    A[k][0] = s * Whh1[2 * k];
    A[k][1] = s * Whh1[2 * k + 1];
  }
  float A2[4];
#pragma unroll
  for (int k = 0; k < 4; ++k) {
    const float s = (k == 2) ? N2LOG2E : NLOG2E;
    A2[k] = s * Whh2[k];
  }
  const int len = lengths[b];
  float* o = out_adj + (size_t)b * TT * 2;

  asm volatile("s_waitcnt vmcnt(0)" ::: "memory");
  __builtin_amdgcn_sched_barrier(0);

  float h0 = 0.f, h1 = 0.f, c0 = 0.f, c1 = 0.f;  // p1 state (H=2)
  float h2 = 0.f, c2 = 0.f;                       // p2 state (H=1)

#pragma unroll 4
  for (int s = 0; s < nst; ++s) {
    const f32x4 ua = SU[s][0][b];   // i0,i1,f0,f1 (pre-scaled)
    const f32x4 ub = SU[s][1][b];   // g0,g1,o0,o1
    const f32x4 uc = SU[s][2][b];   // p2 i,f,g,o

    const float zi0 = fmaf(A[0][0], h0, fmaf(A[0][1], h1, ua[0]));
    const float zi1 = fmaf(A[1][0], h0, fmaf(A[1][1], h1, ua[1]));
    const float zf0 = fmaf(A[2][0], h0, fmaf(A[2][1], h1, ua[2]));
    const float zf1 = fmaf(A[3][0], h0, fmaf(A[3][1], h1, ua[3]));
    const float zg0 = fmaf(A[4][0], h0, fmaf(A[4][1], h1, ub[0]));
    const float zg1 = fmaf(A[5][0], h0, fmaf(A[5][1], h1, ub[1]));
    const float zo0 = fmaf(A[6][0], h0, fmaf(A[6][1], h1, ub[2]));
    const float zo1 = fmaf(A[7][0], h0, fmaf(A[7][1], h1, ub[3]));

    const float si0 = sigm2(zi0), si1 = sigm2(zi1);
    const float sf0 = sigm2(zf0), sf1 = sigm2(zf1);
    const float tg0 = tanh2(zg0), tg1 = tanh2(zg1);
    const float so0 = sigm2(zo0), so1 = sigm2(zo1);

    c0 = fmaf(sf0, c0, si0 * tg0);
    c1 = fmaf(sf1, c1, si1 * tg1);
    h0 = so0 * tanh2(N2LOG2E * c0);
    h1 = so1 * tanh2(N2LOG2E * c1);

    const float yi = fmaf(A2[0], h2, uc[0]);
    const float yf = fmaf(A2[1], h2, uc[1]);
    const float yg = fmaf(A2[2], h2, uc[2]);
    const float yo = fmaf(A2[3], h2, uc[3]);
    c2 = fmaf(sigm2(yf), c2, sigm2(yi) * tanh2(yg));
    h2 = sigm2(yo) * tanh2(N2LOG2E * c2);

    if (s >= sbeg) {                       // stored range
      const int t = tw + s;
      const bool v = t < len;
      const float nw0 = SNW0[s - sbeg][b];
      const float nw1 = SNW1[s - sbeg][b];
      const float a0 = v ? (nw0 - h0 + h2) : nw0;
      const float a1 = v ? (nw1 - h1 + h2) : nw1;
      *(float2*)(o + (size_t)t * 2) = make_float2(a0, a1);
    }
  }
}

extern "C" void kernel_launch(void* const* d_in, const int* in_sizes, int n_in,
                              void* d_out, int out_size, void* d_ws, size_t ws_size,
                              hipStream_t stream) {
  const float* x            = (const float*)d_in[0];
  const int* wt             = (const int*)d_in[1];
  const int* lengths        = (const int*)d_in[2];
  const float* Wnw          = (const float*)d_in[3];
  const float* bnw          = (const float*)d_in[4];
  const float* Ww           = (const float*)d_in[5];
  const float* bw           = (const float*)d_in[6];
  const float* Wih1         = (const float*)d_in[7];
  const float* Whh1         = (const float*)d_in[8];
  const float* bih1         = (const float*)d_in[9];
  const float* bhh1         = (const float*)d_in[10];
  const float* Wih2         = (const float*)d_in[11];
  const float* Whh2         = (const float*)d_in[12];
  const float* bih2         = (const float*)d_in[13];
  const float* bhh2         = (const float*)d_in[14];

  float* out_nw  = (float*)d_out;                       // [B,T,2]
  float* out_adj = (float*)d_out + (size_t)NROWS * 2;   // [B,T,2]
  float* ws      = (float*)d_ws;                        // [T][B][16] floats = 8 MB

  proj_kernel<<<2048, 256, 0, stream>>>(x, wt, Wnw, bnw, Ww, bw,
                                        Wih1, bih1, bhh1, Wih2, bih2, bhh2,
                                        out_nw, ws);
  lstm_kernel<<<NCHUNK, 64, 0, stream>>>(ws, lengths, Whh1, Whh2, out_adj);
}

// Round 14
// 66.094 us; speedup vs baseline: 1.0629x; 1.0629x over previous
//
#include <hip/hip_runtime.h>

#define BB 64
#define TT 2048
#define HH 512
#define NROWS (BB * TT)
#define CS 16     // lstm: output steps per chunk
#define WU 32     // lstm: zero-state warmup steps
#define NST (CS + WU)        // staged steps per block (48)
#define NCHUNK (TT / CS)     // 128 blocks over time

#define NLOG2E  (-1.4426950408889634f)
#define N2LOG2E (-2.8853900817779268f)

typedef float f32x4 __attribute__((ext_vector_type(4)));

// sigmoid(x) where zs = -x*log2(e):   1/(1+2^zs)
static __device__ __forceinline__ float sigm2(float zs) {
  return __builtin_amdgcn_rcpf(1.0f + __builtin_amdgcn_exp2f(zs));
}
// tanh(x) where zs = -2x*log2(e):     2/(1+2^zs) - 1
static __device__ __forceinline__ float tanh2(float zs) {
  return fmaf(2.0f, __builtin_amdgcn_rcpf(1.0f + __builtin_amdgcn_exp2f(zs)), -1.0f);
}
static __device__ __forceinline__ float dot4(f32x4 a, f32x4 b) {
  return fmaf(a.x, b.x, fmaf(a.y, b.y, fmaf(a.z, b.z, a.w * b.w)));
}
// merge-tree reduce: lane%4==c ends up holding sum of a_c over all 64 lanes
static __device__ __forceinline__ float merge_reduce(float a0, float a1, float a2,
                                                     float a3, int lane) {
  float x01 = (lane & 1) ? a1 : a0;
  float y01 = (lane & 1) ? a0 : a1;
  x01 += __shfl_xor(y01, 1, 64);
  float x23 = (lane & 1) ? a3 : a2;
  float y23 = (lane & 1) ? a2 : a3;
  x23 += __shfl_xor(y23, 1, 64);
  float xm = (lane & 2) ? x23 : x01;
  float ym = (lane & 2) ? x01 : x23;
  xm += __shfl_xor(ym, 2, 64);
#pragma unroll
  for (int off = 4; off < 64; off <<= 1) xm += __shfl_xor(xm, off, 64);
  return xm;
}
// async global->LDS: LDS dest is wave-uniform base, HW adds lane*size
static __device__ __forceinline__ void gl16(const float* g, float* l) {
  __builtin_amdgcn_global_load_lds((__attribute__((address_space(1))) const void*)(g),
                                   (__attribute__((address_space(3))) void*)(l), 16, 0, 0);
}
static __device__ __forceinline__ void gl4(const float* g, float* l) {
  __builtin_amdgcn_global_load_lds((__attribute__((address_space(1))) const void*)(g),
                                   (__attribute__((address_space(3))) void*)(l), 4, 0, 0);
}

// Kernel A: projections + where(worry) + LSTM input pre-activations.
// One wave per PAIR of (b,t) rows (r11 structure): 4 loads preissued, two
// independent merge-trees (ILP=2 on the DS chain). PARALLEL tail: lane =
// 16g+k (g<2) computes row r0+g's ws element k in ONE pass (32 active lanes,
// one scatter store for 2x64B).
// ws layout [T][B][16]: u1[0..7] (p1 gates pre-scaled), u2[0..3] (p2), d0, d1, 0, 0.
__global__ __launch_bounds__(256) void proj_kernel(
    const float* __restrict__ x, const int* __restrict__ worry,
    const float* __restrict__ Wnw, const float* __restrict__ bnw,
    const float* __restrict__ Ww,  const float* __restrict__ bw,
    const float* __restrict__ Wih1, const float* __restrict__ bih1, const float* __restrict__ bhh1,
    const float* __restrict__ Wih2, const float* __restrict__ bih2, const float* __restrict__ bhh2,
    float* __restrict__ out_nw, float* __restrict__ ws)
{
  const int lane = threadIdx.x & 63;
  const int wid  = blockIdx.x * (blockDim.x >> 6) + (threadIdx.x >> 6);
  const int nwv  = gridDim.x * (blockDim.x >> 6);
  const int cb   = lane * 4;
  const int g    = (lane >> 4) & 1;  // tail: row within pair
  const int k    = lane & 15;        // tail: ws element 0..15

  const f32x4 wa0 = *(const f32x4*)(Wnw + cb);
  const f32x4 wb0 = *(const f32x4*)(Wnw + 256 + cb);
  const f32x4 wa1 = *(const f32x4*)(Wnw + 512 + cb);
  const f32x4 wb1 = *(const f32x4*)(Wnw + 768 + cb);
  const f32x4 va0 = *(const f32x4*)(Ww  + cb);
  const f32x4 vb0 = *(const f32x4*)(Ww  + 256 + cb);
  const f32x4 va1 = *(const f32x4*)(Ww  + 512 + cb);
  const f32x4 vb1 = *(const f32x4*)(Ww  + 768 + cb);

  // per-lane tail constants: element k of a ws row
  float V0 = 0.f, V1 = 0.f, Bk = 0.f;
  bool selW = false;   // true: input is (w0,w1); false: (d0,d1)
  if (k < 8) {
    const float s = (k == 4 || k == 5) ? N2LOG2E : NLOG2E;
    V0 = s * Wih1[2 * k];
    V1 = s * Wih1[2 * k + 1];
    Bk = s * (bih1[k] + bhh1[k]);
  } else if (k < 12) {
    const int kk = k - 8;
    const float s = (kk == 2) ? N2LOG2E : NLOG2E;
    V0 = s * Wih2[2 * kk];
    V1 = s * Wih2[2 * kk + 1];
    Bk = s * (bih2[kk] + bhh2[kk]);
    selW = true;
  } else if (k == 12) { V0 = 1.f; }
  else if (k == 13) { V1 = 1.f; }
  const float bn0 = bnw[0], bn1 = bnw[1], bw0 = bw[0], bw1 = bw[1];

  for (int r0 = 2 * wid; r0 < NROWS; r0 += 2 * nwv) {
    const float* xr0 = x + (size_t)r0 * HH;
    const float* xr1 = xr0 + HH;
    // 4 loads preissued: 4KB in flight per wave
    const f32x4 xa0 = *(const f32x4*)(xr0 + cb);
    const f32x4 xb0 = *(const f32x4*)(xr0 + 256 + cb);
    const f32x4 xa1 = *(const f32x4*)(xr1 + cb);
    const f32x4 xb1 = *(const f32x4*)(xr1 + 256 + cb);

    const float xmP = merge_reduce(dot4(xa0, wa0) + dot4(xb0, wb0),
                                   dot4(xa0, wa1) + dot4(xb0, wb1),
                                   dot4(xa0, va0) + dot4(xb0, vb0),
                                   dot4(xa0, va1) + dot4(xb0, vb1), lane);
    const float xmQ = merge_reduce(dot4(xa1, wa0) + dot4(xb1, wb0),
                                   dot4(xa1, wa1) + dot4(xb1, wb1),
                                   dot4(xa1, va0) + dot4(xb1, vb0),
                                   dot4(xa1, va1) + dot4(xb1, vb1), lane);

    const float P0 = __shfl(xmP, 0, 64), P1 = __shfl(xmP, 1, 64);
    const float P2 = __shfl(xmP, 2, 64), P3 = __shfl(xmP, 3, 64);
    const float Q0 = __shfl(xmQ, 0, 64), Q1 = __shfl(xmQ, 1, 64);
    const float Q2 = __shfl(xmQ, 2, 64), Q3 = __shfl(xmQ, 3, 64);

    // per-lane A-select for this lane's row (g) — single parallel tail pass
    const float A0 = g ? Q0 : P0;
    const float A1 = g ? Q1 : P1;
    const float A2 = g ? Q2 : P2;
    const float A3 = g ? Q3 : P3;

    const int r = r0 + g;
    const bool useW = selW || (worry[r] != 0);   // worry is int32 (bool->int)
    const float in0 = useW ? (A2 + bw0) : (A0 + bn0);
    const float in1 = useW ? (A3 + bw1) : (A1 + bn1);
    const float u = fmaf(V0, in0, fmaf(V1, in1, Bk));

    if (lane < 32) {
      ws[(((size_t)(r & (TT - 1)) * BB) + (r >> 11)) * 16 + k] = u;
      if (k == 12 || k == 13) out_nw[(size_t)r * 2 + (k - 12)] = u;
    }
  }
}

// Kernel B: time-parallel speculative chunks with LDS-staged inputs (r10).
__global__ __launch_bounds__(64) void lstm_kernel(
    const float* __restrict__ ws, const int* __restrict__ lengths,
    const float* __restrict__ Whh1, const float* __restrict__ Whh2,
    float* __restrict__ out_adj)
{
  __shared__ f32x4 SU[NST][3][64];       // 48*3*64*16 = 147456 B
  __shared__ float SNW0[CS][64];         // 4096 B
  __shared__ float SNW1[CS][64];         // 4096 B   (total 155648 <= 160 KiB)

  const int b = threadIdx.x;             // 0..63 (lane == batch)
  const int chunk = blockIdx.x;
  const int tbeg = chunk * CS;
  const int tw   = (tbeg >= WU) ? (tbeg - WU) : 0;
  const int sbeg = tbeg - tw;            // first stored s (0 for chunk 0)
  const int nst  = sbeg + CS;            // staged steps this block

  // phase 0: async-stage the whole window (no VGPR dests -> cannot be sunk)
  for (int s = 0; s < nst; ++s) {
    const float* row = ws + ((size_t)(tw + s) * BB + b) * 16;  // per-lane src
    gl16(row,     (float*)&SU[s][0][0]);
    gl16(row + 4, (float*)&SU[s][1][0]);
    gl16(row + 8, (float*)&SU[s][2][0]);
    if (s >= sbeg) {
      gl4(row + 12, &SNW0[s - sbeg][0]);
      gl4(row + 13, &SNW1[s - sbeg][0]);
    }
  }

  float A[8][2];
#pragma unroll
  for (int k = 0; k < 8; ++k) {
    const float s = (k == 4 || k == 5) ? N2LOG2E : NLOG2E;
    A[k][0] = s * Whh1[2 * k];
    A[k][1] = s * Whh1[2 * k + 1];
  }
  float A2[4];
#pragma unroll
  for (int k = 0; k < 4; ++k) {
    const float s = (k == 2) ? N2LOG2E : NLOG2E;
    A2[k] = s * Whh2[k];
  }
  const int len = lengths[b];
  float* o = out_adj + (size_t)b * TT * 2;

  asm volatile("s_waitcnt vmcnt(0)" ::: "memory");
  __builtin_amdgcn_sched_barrier(0);

  float h0 = 0.f, h1 = 0.f, c0 = 0.f, c1 = 0.f;  // p1 state (H=2)
  float h2 = 0.f, c2 = 0.f;                       // p2 state (H=1)

#pragma unroll 4
  for (int s = 0; s < nst; ++s) {
    const f32x4 ua = SU[s][0][b];   // i0,i1,f0,f1 (pre-scaled)
    const f32x4 ub = SU[s][1][b];   // g0,g1,o0,o1
    const f32x4 uc = SU[s][2][b];   // p2 i,f,g,o

    const float zi0 = fmaf(A[0][0], h0, fmaf(A[0][1], h1, ua[0]));
    const float zi1 = fmaf(A[1][0], h0, fmaf(A[1][1], h1, ua[1]));
    const float zf0 = fmaf(A[2][0], h0, fmaf(A[2][1], h1, ua[2]));
    const float zf1 = fmaf(A[3][0], h0, fmaf(A[3][1], h1, ua[3]));
    const float zg0 = fmaf(A[4][0], h0, fmaf(A[4][1], h1, ub[0]));
    const float zg1 = fmaf(A[5][0], h0, fmaf(A[5][1], h1, ub[1]));
    const float zo0 = fmaf(A[6][0], h0, fmaf(A[6][1], h1, ub[2]));
    const float zo1 = fmaf(A[7][0], h0, fmaf(A[7][1], h1, ub[3]));

    const float si0 = sigm2(zi0), si1 = sigm2(zi1);
    const float sf0 = sigm2(zf0), sf1 = sigm2(zf1);
    const float tg0 = tanh2(zg0), tg1 = tanh2(zg1);
    const float so0 = sigm2(zo0), so1 = sigm2(zo1);

    c0 = fmaf(sf0, c0, si0 * tg0);
    c1 = fmaf(sf1, c1, si1 * tg1);
    h0 = so0 * tanh2(N2LOG2E * c0);
    h1 = so1 * tanh2(N2LOG2E * c1);

    const float yi = fmaf(A2[0], h2, uc[0]);
    const float yf = fmaf(A2[1], h2, uc[1]);
    const float yg = fmaf(A2[2], h2, uc[2]);
    const float yo = fmaf(A2[3], h2, uc[3]);
    c2 = fmaf(sigm2(yf), c2, sigm2(yi) * tanh2(yg));
    h2 = sigm2(yo) * tanh2(N2LOG2E * c2);

    if (s >= sbeg) {                       // stored range
      const int t = tw + s;
      const bool v = t < len;
      const float nw0 = SNW0[s - sbeg][b];
      const float nw1 = SNW1[s - sbeg][b];
      const float a0 = v ? (nw0 - h0 + h2) : nw0;
      const float a1 = v ? (nw1 - h1 + h2) : nw1;
      *(float2*)(o + (size_t)t * 2) = make_float2(a0, a1);
    }
  }
}

extern "C" void kernel_launch(void* const* d_in, const int* in_sizes, int n_in,
                              void* d_out, int out_size, void* d_ws, size_t ws_size,
                              hipStream_t stream) {
  const float* x            = (const float*)d_in[0];
  const int* wt             = (const int*)d_in[1];
  const int* lengths        = (const int*)d_in[2];
  const float* Wnw          = (const float*)d_in[3];
  const float* bnw          = (const float*)d_in[4];
  const float* Ww           = (const float*)d_in[5];
  const float* bw           = (const float*)d_in[6];
  const float* Wih1         = (const float*)d_in[7];
  const float* Whh1         = (const float*)d_in[8];
  const float* bih1         = (const float*)d_in[9];
  const float* bhh1         = (const float*)d_in[10];
  const float* Wih2         = (const float*)d_in[11];
  const float* Whh2         = (const float*)d_in[12];
  const float* bih2         = (const float*)d_in[13];
  const float* bhh2         = (const float*)d_in[14];

  float* out_nw  = (float*)d_out;                       // [B,T,2]
  float* out_adj = (float*)d_out + (size_t)NROWS * 2;   // [B,T,2]
  float* ws      = (float*)d_ws;                        // [T][B][16] floats = 8 MB

  proj_kernel<<<4096, 256, 0, stream>>>(x, wt, Wnw, bnw, Ww, bw,
                                        Wih1, bih1, bhh1, Wih2, bih2, bhh2,
                                        out_nw, ws);
  lstm_kernel<<<NCHUNK, 64, 0, stream>>>(ws, lengths, Whh1, Whh2, out_adj);
}